// Round 1
// baseline (44.906 us; speedup 1.0000x reference)
//
#include <hip/hip_runtime.h>
#include <math.h>

#define NQ  4
#define DIM 16
#define NL  6

struct Perm { int p[DIM]; };

__host__ __device__ constexpr int cnotp(int c, int t, int idx) {
    return ((idx >> (3 - c)) & 1) ? (idx ^ (1 << (3 - t))) : idx;
}

__host__ __device__ constexpr Perm ring_perm(int r) {
    Perm P{};
    for (int j = 0; j < DIM; ++j) P.p[j] = j;
    for (int i = 0; i < NQ; ++i) {
        Perm Q{};
        for (int j = 0; j < DIM; ++j) Q.p[j] = P.p[cnotp(i, (i + r) % NQ, j)];
        P = Q;
    }
    return P;
}

// ---------------------------------------------------------------------------
// Kernel A: build the fixed 16x16 complex unitary U from weights.
// One wave; threads 0..15 each own one COLUMN of U in registers.
// Layout in ws: U[(j*16+k)*2 + 0] = Re U[j][k], +1 = Im U[j][k].
// ---------------------------------------------------------------------------
__global__ void build_U(const float* __restrict__ w, float* __restrict__ U) {
    const int t = threadIdx.x;
    if (t >= DIM) return;

    float cr[DIM], ci[DIM];
    #pragma unroll
    for (int j = 0; j < DIM; ++j) { cr[j] = (j == t) ? 1.0f : 0.0f; ci[j] = 0.0f; }

    #pragma unroll
    for (int l = 0; l < NL; ++l) {
        #pragma unroll
        for (int i = 0; i < NQ; ++i) {
            const float phi = w[(l * NQ + i) * 3 + 0];
            const float th  = w[(l * NQ + i) * 3 + 1];
            const float om  = w[(l * NQ + i) * 3 + 2];
            const float ct = cosf(0.5f * th), st = sinf(0.5f * th);
            float sp, cp, sm, cm;
            sincosf(0.5f * (phi + om), &sp, &cp);
            sincosf(0.5f * (phi - om), &sm, &cm);
            // Rot(phi, th, om)
            const float g00r =  cp * ct, g00i = -sp * ct;
            const float g01r = -cm * st, g01i = -sm * st;
            const float g10r =  cm * st, g10i = -sm * st;
            const float g11r =  cp * ct, g11i =  sp * ct;

            const int stride = 1 << (3 - i);
            #pragma unroll
            for (int j = 0; j < DIM; ++j) {
                if (j & stride) continue;
                const int j1 = j | stride;
                const float a0r = cr[j],  a0i = ci[j];
                const float a1r = cr[j1], a1i = ci[j1];
                cr[j]  = g00r * a0r - g00i * a0i + g01r * a1r - g01i * a1i;
                ci[j]  = g00r * a0i + g00i * a0r + g01r * a1i + g01i * a1r;
                cr[j1] = g10r * a0r - g10i * a0i + g11r * a1r - g11i * a1i;
                ci[j1] = g10r * a0i + g10i * a0r + g11r * a1i + g11i * a1r;
            }
        }
        // CNOT-ring permutation: new[j] = old[perm[j]]
        constexpr Perm RP[3] = { ring_perm(1), ring_perm(2), ring_perm(3) };
        const Perm& P = RP[l % 3];
        float nr[DIM], ni[DIM];
        #pragma unroll
        for (int j = 0; j < DIM; ++j) { nr[j] = cr[P.p[j]]; ni[j] = ci[P.p[j]]; }
        #pragma unroll
        for (int j = 0; j < DIM; ++j) { cr[j] = nr[j]; ci[j] = ni[j]; }
    }

    #pragma unroll
    for (int j = 0; j < DIM; ++j) {
        U[(j * DIM + t) * 2 + 0] = cr[j];
        U[(j * DIM + t) * 2 + 1] = ci[j];
    }
}

// ---------------------------------------------------------------------------
// Kernel B: per batch element, out = signs . |U v|^2 with v the (real, rank-1)
// encoded state. U is read via wave-uniform addresses -> scalar loads.
// ---------------------------------------------------------------------------
__global__ __launch_bounds__(256) void qsim(const float4* __restrict__ x,
                                            const float* __restrict__ U,
                                            float4* __restrict__ out, int B) {
    const int b = blockIdx.x * blockDim.x + threadIdx.x;
    if (b >= B) return;

    const float4 xv = x[b];
    float c0, s0, c1, s1, c2, s2, c3, s3;
    __sincosf(0.5f * xv.x, &s0, &c0);
    __sincosf(0.5f * xv.y, &s1, &c1);
    __sincosf(0.5f * xv.z, &s2, &c2);
    __sincosf(0.5f * xv.w, &s3, &c3);

    const float pa[4] = { c0 * c1, c0 * s1, s0 * c1, s0 * s1 };
    const float pb[4] = { c2 * c3, c2 * s3, s2 * c3, s2 * s3 };
    float v[DIM];
    #pragma unroll
    for (int a = 0; a < 4; ++a)
        #pragma unroll
        for (int q = 0; q < 4; ++q)
            v[a * 4 + q] = pa[a] * pb[q];

    float acc0 = 0.f, acc1 = 0.f, acc2 = 0.f, acc3 = 0.f;
    #pragma unroll
    for (int j = 0; j < DIM; ++j) {
        float re = 0.f, im = 0.f;
        #pragma unroll
        for (int k = 0; k < DIM; ++k) {
            re = fmaf(U[(j * DIM + k) * 2 + 0], v[k], re);
            im = fmaf(U[(j * DIM + k) * 2 + 1], v[k], im);
        }
        const float p = re * re + im * im;
        acc0 += (j & 8) ? -p : p;   // qubit 0 = MSB
        acc1 += (j & 4) ? -p : p;
        acc2 += (j & 2) ? -p : p;
        acc3 += (j & 1) ? -p : p;
    }
    out[b] = make_float4(acc0, acc1, acc2, acc3);
}

extern "C" void kernel_launch(void* const* d_in, const int* in_sizes, int n_in,
                              void* d_out, int out_size, void* d_ws, size_t ws_size,
                              hipStream_t stream) {
    const float* x = (const float*)d_in[0];        // (B, 4) f32
    const float* w = (const float*)d_in[1];        // (6, 4, 3) f32
    float* U = (float*)d_ws;                       // 16*16*2 f32 = 2 KB
    const int B = in_sizes[0] / NQ;

    build_U<<<1, 64, 0, stream>>>(w, U);
    qsim<<<(B + 255) / 256, 256, 0, stream>>>((const float4*)x, U, (float4*)d_out, B);
}

// Round 2
// 40.310 us; speedup vs baseline: 1.1140x; 1.1140x over previous
//
#include <hip/hip_runtime.h>
#include <math.h>

#define NQ   4
#define DIM  16
#define NL   6
#define ELEM 4
#define TPB  256

struct Perm { int p[DIM]; };

__host__ __device__ constexpr int cnotp(int c, int t, int idx) {
    return ((idx >> (3 - c)) & 1) ? (idx ^ (1 << (3 - t))) : idx;
}

__host__ __device__ constexpr Perm ring_perm(int r) {
    Perm P{};
    for (int j = 0; j < DIM; ++j) P.p[j] = j;
    for (int i = 0; i < NQ; ++i) {
        Perm Q{};
        for (int j = 0; j < DIM; ++j) Q.p[j] = P.p[cnotp(i, (i + r) % NQ, j)];
        P = Q;
    }
    return P;
}

// ---------------------------------------------------------------------------
// Kernel A: build the fixed 16x16 complex unitary U from weights (one wave,
// threads 0..15 each own a column). Fast-math sincos: angles ~N(0,1), output
// tolerance is 1.6e-2 so ~1e-6 trig error is irrelevant.
// Layout: U[(j*16+k)*2 + 0] = Re U[j][k], +1 = Im U[j][k]  (row-major rows).
// ---------------------------------------------------------------------------
__global__ void build_U(const float* __restrict__ w, float* __restrict__ U) {
    const int t = threadIdx.x;
    if (t >= DIM) return;

    float cr[DIM], ci[DIM];
    #pragma unroll
    for (int j = 0; j < DIM; ++j) { cr[j] = (j == t) ? 1.0f : 0.0f; ci[j] = 0.0f; }

    #pragma unroll
    for (int l = 0; l < NL; ++l) {
        #pragma unroll
        for (int i = 0; i < NQ; ++i) {
            const float phi = w[(l * NQ + i) * 3 + 0];
            const float th  = w[(l * NQ + i) * 3 + 1];
            const float om  = w[(l * NQ + i) * 3 + 2];
            float ct, st, sp, cp, sm, cm;
            __sincosf(0.5f * th, &st, &ct);
            __sincosf(0.5f * (phi + om), &sp, &cp);
            __sincosf(0.5f * (phi - om), &sm, &cm);
            const float g00r =  cp * ct, g00i = -sp * ct;
            const float g01r = -cm * st, g01i = -sm * st;
            const float g10r =  cm * st, g10i = -sm * st;
            const float g11r =  cp * ct, g11i =  sp * ct;

            const int stride = 1 << (3 - i);
            #pragma unroll
            for (int j = 0; j < DIM; ++j) {
                if (j & stride) continue;
                const int j1 = j | stride;
                const float a0r = cr[j],  a0i = ci[j];
                const float a1r = cr[j1], a1i = ci[j1];
                cr[j]  = g00r * a0r - g00i * a0i + g01r * a1r - g01i * a1i;
                ci[j]  = g00r * a0i + g00i * a0r + g01r * a1i + g01i * a1r;
                cr[j1] = g10r * a0r - g10i * a0i + g11r * a1r - g11i * a1i;
                ci[j1] = g10r * a0i + g10i * a0r + g11r * a1i + g11i * a1r;
            }
        }
        constexpr Perm RP[3] = { ring_perm(1), ring_perm(2), ring_perm(3) };
        const Perm& P = RP[l % 3];
        float nr[DIM], ni[DIM];
        #pragma unroll
        for (int j = 0; j < DIM; ++j) { nr[j] = cr[P.p[j]]; ni[j] = ci[P.p[j]]; }
        #pragma unroll
        for (int j = 0; j < DIM; ++j) { cr[j] = nr[j]; ci[j] = ni[j]; }
    }

    #pragma unroll
    for (int j = 0; j < DIM; ++j) {
        U[(j * DIM + t) * 2 + 0] = cr[j];
        U[(j * DIM + t) * 2 + 1] = ci[j];
    }
}

// ---------------------------------------------------------------------------
// Kernel B: ELEM=4 batch elements per thread. Row j of U is loaded once into
// 8 float4 registers and reused across all 4 elements (4x load amortization).
// Element mapping tid + e*T keeps x/out accesses fully coalesced.
// ---------------------------------------------------------------------------
__global__ __launch_bounds__(TPB) void qsim(const float4* __restrict__ x,
                                            const float* __restrict__ U,
                                            float4* __restrict__ out, int T) {
    const int tid = blockIdx.x * TPB + threadIdx.x;
    if (tid >= T) return;

    float v[ELEM][DIM];
    #pragma unroll
    for (int e = 0; e < ELEM; ++e) {
        const float4 xv = x[tid + e * T];
        float c0, s0, c1, s1, c2, s2, c3, s3;
        __sincosf(0.5f * xv.x, &s0, &c0);
        __sincosf(0.5f * xv.y, &s1, &c1);
        __sincosf(0.5f * xv.z, &s2, &c2);
        __sincosf(0.5f * xv.w, &s3, &c3);
        const float pa[4] = { c0 * c1, c0 * s1, s0 * c1, s0 * s1 };
        const float pb[4] = { c2 * c3, c2 * s3, s2 * c3, s2 * s3 };
        #pragma unroll
        for (int a = 0; a < 4; ++a)
            #pragma unroll
            for (int q = 0; q < 4; ++q)
                v[e][a * 4 + q] = pa[a] * pb[q];
    }

    float acc[ELEM][4] = {};
    const float4* __restrict__ U4 = (const float4*)U;

    #pragma unroll
    for (int j = 0; j < DIM; ++j) {
        float4 r[8];
        #pragma unroll
        for (int m = 0; m < 8; ++m) r[m] = U4[j * 8 + m];   // row j: (re,im) pairs
        #pragma unroll
        for (int e = 0; e < ELEM; ++e) {
            float re = 0.f, im = 0.f;
            #pragma unroll
            for (int m = 0; m < 8; ++m) {
                re = fmaf(r[m].x, v[e][2 * m + 0], re);
                im = fmaf(r[m].y, v[e][2 * m + 0], im);
                re = fmaf(r[m].z, v[e][2 * m + 1], re);
                im = fmaf(r[m].w, v[e][2 * m + 1], im);
            }
            const float p = re * re + im * im;
            acc[e][0] += (j & 8) ? -p : p;   // qubit 0 = MSB
            acc[e][1] += (j & 4) ? -p : p;
            acc[e][2] += (j & 2) ? -p : p;
            acc[e][3] += (j & 1) ? -p : p;
        }
    }

    #pragma unroll
    for (int e = 0; e < ELEM; ++e)
        out[tid + e * T] = make_float4(acc[e][0], acc[e][1], acc[e][2], acc[e][3]);
}

extern "C" void kernel_launch(void* const* d_in, const int* in_sizes, int n_in,
                              void* d_out, int out_size, void* d_ws, size_t ws_size,
                              hipStream_t stream) {
    const float* x = (const float*)d_in[0];        // (B, 4) f32
    const float* w = (const float*)d_in[1];        // (6, 4, 3) f32
    float* U = (float*)d_ws;                       // 16*16*2 f32 = 2 KB
    const int B = in_sizes[0] / NQ;
    const int T = B / ELEM;

    build_U<<<1, 64, 0, stream>>>(w, U);
    qsim<<<(T + TPB - 1) / TPB, TPB, 0, stream>>>((const float4*)x, U, (float4*)d_out, T);
}